// Round 2
// baseline (6970.009 us; speedup 1.0000x reference)
//
#include <hip/hip_runtime.h>
#include <hip/hip_bf16.h>

// Problem constants
#define B_   16
#define T_   16
#define H_   161
#define W_   181
#define C_   3
#define F_   21
#define F4_  84
#define CIN_ 24          // C_ + F_ combined conv input channels
#define TS   16          // spatial tile (TS x TS positions per 256-thread block)
#define TP   18          // tile + 3x3 halo
#define NPOS (TP*TP)     // 324

__device__ __forceinline__ float hsig(float x) {
  // Keras hard_sigmoid: clip(0.2x + 0.5, 0, 1)
  return fminf(fmaxf(0.2f * x + 0.5f, 0.0f), 1.0f);
}

__device__ __forceinline__ float fast_tanh(float x) {
  // tanh(x) = sign(x) * (1 - e^{-2|x|}) / (1 + e^{-2|x|}); e^{-2|x|} in (0,1] -> no overflow
  float ax = fabsf(x);
  float t = __expf(-2.0f * ax);                       // v_exp_f32 path
  float r = (1.0f - t) * __builtin_amdgcn_rcpf(1.0f + t);
  return copysignf(r, x);
}

// Combine input + recurrent kernels into one fp32 weight tensor W[kk][ci][f4]
// (kk = ky*3+kx in 0..8, ci: 0..2 from input kernel, 3..23 from recurrent kernel)
__global__ void prep_kernel(const float* __restrict__ k,
                            const float* __restrict__ rk,
                            const float* __restrict__ bias,
                            float* __restrict__ Wf, float* __restrict__ biasf) {
  int i = blockIdx.x * 256 + threadIdx.x;
  if (i < 9 * CIN_ * F4_) {
    int f4   = i % F4_;
    int rest = i / F4_;
    int ci   = rest % CIN_;
    int kk   = rest / CIN_;
    float v;
    if (ci < C_) v = k[(kk * C_ + ci) * F4_ + f4];
    else         v = rk[(kk * F_ + (ci - C_)) * F4_ + f4];
    Wf[i] = v;
  }
  if (i < F4_) biasf[i] = bias[i];
}

// One ConvLSTM time step: z = conv(concat(x_t, h_prev)) + bias; gates; update c,h.
// grid: (ceil(W/TS), ceil(H/TS), B), block: 256 = TS*TS
__global__ __launch_bounds__(256, 2) void step_kernel(
    const float* __restrict__ x,       // (B,T,H,W,C) fp32
    const float* __restrict__ Wf,      // [9][24][84]
    const float* __restrict__ biasf,   // [84]
    const float* __restrict__ h_in,    // (B,H,W,F) fp32 (ignored if first)
    float* __restrict__ h_out,        // (B,H,W,F) fp32 (not written if last)
    float* __restrict__ c_buf,        // (B,H,W,F) fp32 in-place
    const float* __restrict__ mask,   // (H,W,1) fp32
    float* __restrict__ out,          // (B,H,W,F) fp32, written only if last
    int t, int first, int last) {
  __shared__ float tile[CIN_][NPOS + 1];  // channel-major: stride-1 spatial reads

  int b   = blockIdx.z;
  int by0 = blockIdx.y * TS;
  int bx0 = blockIdx.x * TS;

  // Stage input tile (with halo, zero-padded) into LDS.
  for (int i = threadIdx.x; i < CIN_ * NPOS; i += 256) {
    int ci  = i / NPOS;
    int pos = i - ci * NPOS;
    int py  = pos / TP;
    int px  = pos - py * TP;
    int gy  = by0 - 1 + py;
    int gx  = bx0 - 1 + px;
    float v = 0.0f;
    if ((unsigned)gy < (unsigned)H_ && (unsigned)gx < (unsigned)W_) {
      if (ci < C_) {
        v = x[(((size_t)(b * T_ + t) * H_ + gy) * W_ + gx) * C_ + ci];
      } else if (!first) {
        v = h_in[((size_t)(b * H_ + gy) * W_ + gx) * F_ + (ci - C_)];
      }
    }
    tile[ci][pos] = v;
  }
  __syncthreads();

  int tx = threadIdx.x & 15;
  int ty = threadIdx.x >> 4;
  int gy = by0 + ty;
  int gx = bx0 + tx;

  float acc[F4_];
#pragma unroll
  for (int j = 0; j < F4_; ++j) acc[j] = biasf[j];

  // 216 (kk,ci) iterations x 84 FMA: v from LDS (VGPR), w block-uniform (scalar loads)
  for (int kk = 0; kk < 9; ++kk) {
    int ky = kk / 3;
    int kx = kk - 3 * ky;
    int pbase = (ty + ky) * TP + (tx + kx);
    const float* wbase = Wf + kk * (CIN_ * F4_);
#pragma unroll 1
    for (int ci = 0; ci < CIN_; ++ci) {
      float v = tile[ci][pbase];
      const float* w = wbase + ci * F4_;
#pragma unroll
      for (int j = 0; j < F4_; ++j) acc[j] = fmaf(v, w[j], acc[j]);
    }
  }

  if (gy < H_ && gx < W_) {
    size_t p  = (size_t)(b * H_ + gy) * W_ + gx;
    size_t pf = p * F_;
    float m = last ? mask[gy * W_ + gx] : 0.0f;
#pragma unroll
    for (int f = 0; f < F_; ++f) {
      float ig = hsig(acc[f]);
      float fg = hsig(acc[F_ + f]);
      float gg = fast_tanh(acc[2 * F_ + f]);
      float og = hsig(acc[3 * F_ + f]);
      float cp = first ? 0.0f : c_buf[pf + f];
      float cn = fg * cp + ig * gg;
      float hn = og * fast_tanh(cn);
      c_buf[pf + f] = cn;
      if (!last) h_out[pf + f] = hn;
      else       out[pf + f]   = hn * m;
    }
  }
}

extern "C" void kernel_launch(void* const* d_in, const int* in_sizes, int n_in,
                              void* d_out, int out_size, void* d_ws, size_t ws_size,
                              hipStream_t stream) {
  const float* x  = (const float*)d_in[0];
  const float* k  = (const float*)d_in[1];
  const float* rk = (const float*)d_in[2];
  const float* bs = (const float*)d_in[3];
  const float* mk = (const float*)d_in[4];
  float* outF = (float*)d_out;   // (B,H,W,F) fp32 = 39.17 MB; doubles as odd-step h buffer

  char* ws = (char*)d_ws;
  float* Wf    = (float*)ws;                       // 9*24*84 = 18144 fp32
  float* biasf = Wf + 9 * CIN_ * F4_;              // 84 fp32
  size_t off = (((size_t)(9 * CIN_ * F4_ + F4_) * 4) + 255) & ~(size_t)255;
  size_t HWF = (size_t)B_ * H_ * W_ * F_;          // 9,791,376
  float* hA = (float*)(ws + off);                  // even-step h output
  float* cB = hA + HWF;                            // cell state, in-place
  // total ws use: ~78.4 MB

  prep_kernel<<<dim3((9 * CIN_ * F4_ + 255) / 256), 256, 0, stream>>>(k, rk, bs, Wf, biasf);

  dim3 grid((W_ + TS - 1) / TS, (H_ + TS - 1) / TS, B_);  // (12, 11, 16)
  for (int t = 0; t < T_; ++t) {
    // even t: read outF (h from odd t-1), write hA; odd t: read hA, write outF.
    // t=0: h_in unused (first=1). t=15 (last): h_out not written; out=d_out written.
    const float* hi = (t & 1) ? hA : outF;
    float* ho       = (t & 1) ? outF : hA;
    step_kernel<<<grid, 256, 0, stream>>>(x, Wf, biasf, hi, ho, cB, mk, outF,
                                          t, (t == 0) ? 1 : 0, (t == T_ - 1) ? 1 : 0);
  }
}